// Round 11
// baseline (163.177 us; speedup 1.0000x reference)
//
#include <hip/hip_runtime.h>
#include <math.h>

#define HID 128
#define TILE_R 64
#define TILE_P 32          // precompute row tile
#define XS_STRIDE 132      // fp32 staging stride (K1)
#define H0S_STRIDE 136     // bf16 LDS stride in shorts: 272 B = 68 dwords == 4 mod 32 banks
#define DELTA 0.05f        // per-score qualify margin (R3/R6-validated)
#define MAIN_GRID 768      // 3 blocks/CU x 256 CUs: fully co-resident persistent main

typedef short bf16x8 __attribute__((ext_vector_type(8)));
typedef float f32x4 __attribute__((ext_vector_type(4)));

static __device__ __forceinline__ unsigned short f2bf(float f) {
    union { float f; unsigned u; } v; v.f = f;
    unsigned r = v.u + 0x7FFFu + ((v.u >> 16) & 1u);   // RNE
    return (unsigned short)(r >> 16);
}
static __device__ __forceinline__ float bflo(unsigned u) {
    union { unsigned u; float f; } v; v.u = u << 16; return v.f;
}
static __device__ __forceinline__ float bfhi(unsigned u) {
    union { unsigned u; float f; } v; v.u = u & 0xFFFF0000u; return v.f;
}
// order-preserving float<->u32 packing for atomicMax
static __device__ __forceinline__ unsigned mono32(float f) {
    unsigned u = __float_as_uint(f);
    return (u & 0x80000000u) ? ~u : (u | 0x80000000u);
}
static __device__ __forceinline__ float unmono32(unsigned k) {
    return __uint_as_float((k & 0x80000000u) ? (k ^ 0x80000000u) : ~k);
}

#define FMA4(avc, wv)                         \
    acc[r][0] = fmaf(avc, wv.x, acc[r][0]);   \
    acc[r][1] = fmaf(avc, wv.y, acc[r][1]);   \
    acc[r][2] = fmaf(avc, wv.z, acc[r][2]);   \
    acc[r][3] = fmaf(avc, wv.w, acc[r][3]);

// ---------------------------------------------------------------------------
// K1: g = x_graph @ W0[0:256] + b0 (fp32); Pbf = bf16 node partials;
//     W1T = bf16 W1 transpose; zero misc {gmax, counter, key}.
// ---------------------------------------------------------------------------
__global__ __launch_bounds__(256, 4) void precompute_kernel(
    const float* __restrict__ x_graph,
    const float* __restrict__ x_m,
    const float* __restrict__ x_job,
    const float* __restrict__ W0,
    const float* __restrict__ b0,
    const float* __restrict__ W1,
    float* __restrict__ g,
    unsigned short* __restrict__ Pbf,
    unsigned short* __restrict__ W1T,
    unsigned* __restrict__ misc,
    int M, int J, int aTiles, int bTiles)
{
    const int t = threadIdx.x;
    const int bid = blockIdx.x;

    if (bid == 0) {
        if (t == 0) {
            misc[0] = 0u;                                  // gmax (mono-packed)
            misc[1] = 0u;                                  // completion counter
            *(unsigned long long*)(misc + 2) = 0ull;       // winner key
        }
        __shared__ float xg[2 * HID];
        if (t < HID) { xg[t] = x_graph[t]; xg[t + HID] = x_graph[t + HID]; }
        __syncthreads();
        if (t < HID) {
            float acc = b0[t];
            #pragma unroll 8
            for (int k = 0; k < 2 * HID; ++k)
                acc = fmaf(xg[k], W0[k * HID + t], acc);
            g[t] = acc;
        }
        return;
    }
    if (bid == 1 + aTiles + bTiles) {
        for (int e = t; e < HID * HID; e += 256) {
            int n = e >> 7, k = e & 127;
            W1T[e] = f2bf(W1[k * HID + n]);
        }
        return;
    }

    const int tb = bid - 1;
    const float* X;
    const float* W;
    int r0, nr, dstBase;
    if (tb < aTiles) {
        r0 = tb * TILE_P;
        nr = min(TILE_P, M - r0);
        X = x_m + (size_t)r0 * HID;
        W = W0 + 2 * HID * HID;
        dstBase = r0;
    } else {
        int jb = tb - aTiles;
        r0 = jb * TILE_P;
        nr = min(TILE_P, J - r0);
        X = x_job + (size_t)r0 * HID;
        W = W0 + 3 * HID * HID;
        dstBase = M + r0;
    }

    __shared__ float xs[TILE_P * XS_STRIDE];
    {
        int row = t >> 3;
        int e = t & 7;
        #pragma unroll
        for (int u = 0; u < 4; ++u) {
            int c = e * 16 + u * 4;
            float4 v = (row < nr) ? *(const float4*)(X + row * HID + c)
                                  : make_float4(0.f, 0.f, 0.f, 0.f);
            *(float4*)&xs[row * XS_STRIDE + c] = v;
        }
    }
    __syncthreads();

    const int w = t >> 6;
    const int l = t & 63;
    const int tc = l & 7;
    const int tr = l >> 3;
    const int c0 = w * 32 + tc * 4;

    float acc[4][4];
    #pragma unroll
    for (int r = 0; r < 4; ++r)
        #pragma unroll
        for (int c = 0; c < 4; ++c) acc[r][c] = 0.0f;

    #pragma unroll 2
    for (int k0 = 0; k0 < HID; k0 += 4) {
        float4 w0v = *(const float4*)(W + (k0 + 0) * HID + c0);
        float4 w1v = *(const float4*)(W + (k0 + 1) * HID + c0);
        float4 w2m = *(const float4*)(W + (k0 + 2) * HID + c0);
        float4 w3v = *(const float4*)(W + (k0 + 3) * HID + c0);
        #pragma unroll
        for (int r = 0; r < 4; ++r) {
            float4 a = *(const float4*)&xs[(r * 8 + tr) * XS_STRIDE + k0];
            FMA4(a.x, w0v)
            FMA4(a.y, w1v)
            FMA4(a.z, w2m)
            FMA4(a.w, w3v)
        }
    }

    #pragma unroll
    for (int r = 0; r < 4; ++r) {
        int row = r * 8 + tr;
        if (row < nr) {
            unsigned lo0 = (unsigned)f2bf(acc[r][0]) | ((unsigned)f2bf(acc[r][1]) << 16);
            unsigned lo1 = (unsigned)f2bf(acc[r][2]) | ((unsigned)f2bf(acc[r][3]) << 16);
            uint2 pk = make_uint2(lo0, lo1);
            *(uint2*)(Pbf + (size_t)(dstBase + row) * HID + c0) = pk;
        }
    }
}

// ---------------------------------------------------------------------------
// K2: grid-stride persistent main. W1T->LDS once/block; per tile: bf16 h0
//     gather, MFMA h1, fused epilogue -> scores + partial. Tile-max published
//     via fire-and-forget atomicMax(gmax) (no return -> no wait; visible to
//     the next kernel via kernel-boundary coherence). No fences.
// ---------------------------------------------------------------------------
__global__ __launch_bounds__(256, 3) void main_kernel(
    const int* __restrict__ m_ids,
    const int* __restrict__ job_idx,
    const float* __restrict__ b1,
    const float* __restrict__ W2,
    const float* __restrict__ b2,
    const float* __restrict__ g,
    const unsigned short* __restrict__ Pbf,
    const unsigned short* __restrict__ W1T,
    float* __restrict__ scores,
    float4* __restrict__ partials,
    unsigned* __restrict__ misc,
    int N, int M, int tiles)
{
    __shared__ __align__(16) short h0s[TILE_R * H0S_STRIDE];
    __shared__ __align__(16) short w1s[HID * H0S_STRIDE];
    __shared__ float sred[TILE_R];

    const int t = threadIdx.x;
    const int l = t & 63;
    const int w = t >> 6;
    const int quad = l >> 4;
    const int mrow = l & 15;

    {
        const uint4* src = (const uint4*)W1T;        // 2048 x 16B
        #pragma unroll
        for (int e = t; e < 2048; e += 256) {
            int n = e >> 4, pos = e & 15;
            *(uint4*)&w1s[n * H0S_STRIDE + pos * 8] = src[e];
        }
    }

    for (int tile = blockIdx.x; tile < tiles; tile += MAIN_GRID) {
        const int row0 = tile * TILE_R;

        {
            int row = t >> 2;
            int q = t & 3;
            int grow = row0 + row;
            int gr = (grow < N) ? grow : (N - 1);
            int m = m_ids[gr];
            int j = job_idx[gr];
            const unsigned short* pm = Pbf + (size_t)m * HID + q * 32;
            const unsigned short* pj = Pbf + (size_t)(M + j) * HID + q * 32;
            const float* gp = g + q * 32;
            short* dst = &h0s[row * H0S_STRIDE + q * 32];
            #pragma unroll
            for (int u = 0; u < 4; ++u) {
                uint4 mv = *(const uint4*)(pm + u * 8);
                uint4 jv = *(const uint4*)(pj + u * 8);
                float4 g0 = *(const float4*)(gp + u * 8);
                float4 g1 = *(const float4*)(gp + u * 8 + 4);
                float h0v = fmaxf(bflo(mv.x) + bflo(jv.x) + g0.x, 0.f);
                float h1v = fmaxf(bfhi(mv.x) + bfhi(jv.x) + g0.y, 0.f);
                float h2v = fmaxf(bflo(mv.y) + bflo(jv.y) + g0.z, 0.f);
                float h3v = fmaxf(bfhi(mv.y) + bfhi(jv.y) + g0.w, 0.f);
                float h4v = fmaxf(bflo(mv.z) + bflo(jv.z) + g1.x, 0.f);
                float h5v = fmaxf(bfhi(mv.z) + bfhi(jv.z) + g1.y, 0.f);
                float h6v = fmaxf(bflo(mv.w) + bflo(jv.w) + g1.z, 0.f);
                float h7v = fmaxf(bfhi(mv.w) + bfhi(jv.w) + g1.w, 0.f);
                uint4 pk;
                pk.x = (unsigned)f2bf(h0v) | ((unsigned)f2bf(h1v) << 16);
                pk.y = (unsigned)f2bf(h2v) | ((unsigned)f2bf(h3v) << 16);
                pk.z = (unsigned)f2bf(h4v) | ((unsigned)f2bf(h5v) << 16);
                pk.w = (unsigned)f2bf(h6v) | ((unsigned)f2bf(h7v) << 16);
                *(uint4*)(dst + u * 8) = pk;
            }
        }
        __syncthreads();                       // h0s (+w1s on 1st iter) ready

        bf16x8 af[4];
        const short* ab = &h0s[(w * 16 + mrow) * H0S_STRIDE + quad * 8];
        #pragma unroll
        for (int kc = 0; kc < 4; ++kc)
            af[kc] = *(const bf16x8*)(ab + kc * 32);

        f32x4 acc[8];
        #pragma unroll
        for (int nt = 0; nt < 8; ++nt) {
            f32x4 z = {0.f, 0.f, 0.f, 0.f};
            acc[nt] = z;
        }

        const short* bb = &w1s[mrow * H0S_STRIDE + quad * 8];
        #pragma unroll
        for (int nt = 0; nt < 8; ++nt) {
            #pragma unroll
            for (int kc = 0; kc < 4; ++kc) {
                bf16x8 bfr = *(const bf16x8*)(bb + nt * 16 * H0S_STRIDE + kc * 32);
                acc[nt] = __builtin_amdgcn_mfma_f32_16x16x32_bf16(af[kc], bfr, acc[nt], 0, 0, 0);
            }
        }

        float p0 = 0.f, p1 = 0.f, p2 = 0.f, p3 = 0.f;
        #pragma unroll
        for (int nt = 0; nt < 8; ++nt) {
            int c = nt * 16 + mrow;
            float b1v = b1[c], w2v = W2[c];
            p0 += fmaxf(acc[nt][0] + b1v, 0.f) * w2v;
            p1 += fmaxf(acc[nt][1] + b1v, 0.f) * w2v;
            p2 += fmaxf(acc[nt][2] + b1v, 0.f) * w2v;
            p3 += fmaxf(acc[nt][3] + b1v, 0.f) * w2v;
        }
        #pragma unroll
        for (int off = 1; off < 16; off <<= 1) {
            p0 += __shfl_xor(p0, off);
            p1 += __shfl_xor(p1, off);
            p2 += __shfl_xor(p2, off);
            p3 += __shfl_xor(p3, off);
        }
        if (mrow == 0) {
            int rb = w * 16 + quad * 4;
            sred[rb + 0] = p0;
            sred[rb + 1] = p1;
            sred[rb + 2] = p2;
            sred[rb + 3] = p3;
        }
        __syncthreads();                       // sred ready; af in regs -> h0s free

        if (t < 64) {
            int grow = row0 + t;
            float s = sred[t] + b2[0];
            if (grow < N) scores[grow] = s;
            else s = -1e30f;

            float mmax = s;
            int midx = grow;
            #pragma unroll
            for (int off = 1; off < 64; off <<= 1) {
                float om = __shfl_xor(mmax, off);
                int oi = __shfl_xor(midx, off);
                if (om > mmax || (om == mmax && oi < midx)) { mmax = om; midx = oi; }
            }
            float d = s - mmax;
            float e = expf(d);
            float z = e;
            float ss = d * e;
            #pragma unroll
            for (int off = 1; off < 64; off <<= 1) {
                z += __shfl_xor(z, off);
                ss += __shfl_xor(ss, off);
            }
            if (t == 0) {
                partials[tile] = make_float4(mmax, z, ss, (float)midx);
                atomicMax(&misc[0], mono32(mmax));   // fire-and-forget
            }
        }
    }
}

// ---------------------------------------------------------------------------
__device__ inline void sm_merge(float& am, float& az, float& ass, int& ai,
                                float bm, float bz, float bss, int bi)
{
    if (bm > am || (bm == am && bi < ai)) {
        float tm = am, tz = az, ts = ass; int ti = ai;
        am = bm; az = bz; ass = bss; ai = bi;
        bm = tm; bz = tz; bss = ts; bi = ti;
    }
    float f = expf(bm - am);
    az += bz * f;
    ass += (bss + (bm - am) * bz) * f;
}

// ---------------------------------------------------------------------------
// K3: fused scan+finalize. cut = unmono(gmax) - DELTA (single scalar load).
//   Per-block candidates (<=256 by construction), exact fp32 rescore
//   (register+shfl), candidate blocks publish packed u64 key via atomicMax
//   (R3-validated pattern, fence-free: counter increment data-depends on the
//   atomicMax return, forcing vmcnt drain before the add). Last block merges
//   partials + reads key -> out[0..3].
// ---------------------------------------------------------------------------
__global__ __launch_bounds__(256) void scan_kernel(
    const float4* __restrict__ partials, int nparts,
    const float* __restrict__ scores,
    const int* __restrict__ m_ids,
    const int* __restrict__ job_idx,
    const float* __restrict__ x_m,
    const float* __restrict__ x_job,
    const float* __restrict__ W0,
    const float* __restrict__ W1,
    const float* __restrict__ b1,
    const float* __restrict__ W2,
    const float* __restrict__ b2,
    const float* __restrict__ g,
    unsigned* __restrict__ misc,
    float* __restrict__ out,
    int N)
{
    __shared__ int cand[256];
    __shared__ int ccount;
    __shared__ float rs[4];
    __shared__ int ri[4];
    __shared__ int lastFlag;
    __shared__ float4 wred[4];
    __shared__ int widx[4];

    const int t = threadIdx.x;
    const int w = t >> 6;
    const int l = t & 63;
    const int base = blockIdx.x * 256;
    unsigned long long* keyp = (unsigned long long*)(misc + 2);

    if (t == 0) ccount = 0;
    __syncthreads();

    const float mhat_bf = unmono32(misc[0]);
    const float cut = mhat_bf - DELTA;

    int idx = base + t;
    if (idx < N && scores[idx] >= cut) {
        int p = atomicAdd(&ccount, 1);  // LDS atomic; p < 256 guaranteed
        cand[p] = idx;
    }
    __syncthreads();
    const int nc = ccount;

    float bs = -1e30f;
    int bi = 0x7fffffff;
    for (int c = w; c < nc; c += 4) {
        int gr = cand[c];
        int mm = m_ids[gr];
        int jj = job_idx[gr];
        const float* xm = x_m + (size_t)mm * HID;
        const float* xj = x_job + (size_t)jj * HID;
        const float* wm = W0 + 2 * HID * HID;
        const float* wj = W0 + 3 * HID * HID;
        float a0 = g[l], a1 = g[l + 64];
        for (int k = 0; k < HID; ++k) {
            float xmk = xm[k];
            float xjk = xj[k];
            a0 = fmaf(xmk, wm[k * HID + l], a0);
            a1 = fmaf(xmk, wm[k * HID + l + 64], a1);
            a0 = fmaf(xjk, wj[k * HID + l], a0);
            a1 = fmaf(xjk, wj[k * HID + l + 64], a1);
        }
        a0 = fmaxf(a0, 0.f);
        a1 = fmaxf(a1, 0.f);
        float acc0 = 0.f, acc1 = 0.f;
        for (int k = 0; k < 64; ++k) {
            float h = __shfl(a0, k);
            acc0 = fmaf(h, W1[k * HID + l], acc0);
            acc1 = fmaf(h, W1[k * HID + l + 64], acc1);
        }
        for (int k = 0; k < 64; ++k) {
            float h = __shfl(a1, k);
            acc0 = fmaf(h, W1[(k + 64) * HID + l], acc0);
            acc1 = fmaf(h, W1[(k + 64) * HID + l + 64], acc1);
        }
        float p = fmaxf(acc0 + b1[l], 0.f) * W2[l]
                + fmaxf(acc1 + b1[l + 64], 0.f) * W2[l + 64];
        #pragma unroll
        for (int off = 1; off < 64; off <<= 1)
            p += __shfl_xor(p, off);
        float s = p + b2[0];
        if (s > bs || (s == bs && gr < bi)) { bs = s; bi = gr; }
    }
    if (l == 0) { rs[w] = bs; ri[w] = bi; }
    __syncthreads();

    if (t == 0) {
        float best = rs[0];
        int bwin = ri[0];
        for (int i2 = 1; i2 < 4; ++i2)
            if (rs[i2] > best || (rs[i2] == best && ri[i2] < bwin)) {
                best = rs[i2]; bwin = ri[i2];
            }
        unsigned inc = 1u;
        if (nc > 0) {
            unsigned long long mykey =
                ((unsigned long long)mono32(best) << 32)
                | (unsigned long long)(0xFFFFFFFFu - (unsigned)bwin);
            unsigned long long old = atomicMax(keyp, mykey);
            // data-depend inc on old: forces vmcnt drain of the key write
            // before the counter add (old == mykey is impossible: idx unique)
            inc = (old == mykey) ? 2u : 1u;
        }
        unsigned total = atomicAdd(&misc[1], inc) + inc;
        lastFlag = (total == (unsigned)gridDim.x) ? 1 : 0;
    }
    __syncthreads();

    if (lastFlag) {
        // ---- last block: merge partials (softmax stats) + winner -> out ----
        float m = -1e30f, z = 0.f, ss = 0.f;
        int midx = 0x7fffffff;
        for (int i = t; i < nparts; i += 256) {
            float4 p = partials[i];
            sm_merge(m, z, ss, midx, p.x, p.y, p.z, (int)p.w);
        }
        #pragma unroll
        for (int off = 1; off < 64; off <<= 1) {
            float om = __shfl_xor(m, off);
            float oz = __shfl_xor(z, off);
            float os = __shfl_xor(ss, off);
            int oi = __shfl_xor(midx, off);
            sm_merge(m, z, ss, midx, om, oz, os, oi);
        }
        if (l == 0) { wred[w] = make_float4(m, z, ss, 0.f); widx[w] = midx; }
        __syncthreads();
        if (t == 0) {
            for (int i = 1; i < 4; ++i)
                sm_merge(m, z, ss, midx, wred[i].x, wred[i].y, wred[i].z, widx[i]);
            unsigned long long key = atomicMax(keyp, 0ull);   // coherent read
            float swin = unmono32((unsigned)(key >> 32));
            int iwin = (int)(0xFFFFFFFFu - (unsigned)(key & 0xFFFFFFFFu));
            float logZ = logf(z);
            out[0] = (float)iwin;           // exact argmax
            out[1] = expf(swin - m) / z;    // probs[idx]
            out[2] = (swin - m) - logZ;     // logp[idx]
            out[3] = logZ - ss / z;         // entropy
        }
    }
}

// ---------------------------------------------------------------------------
extern "C" void kernel_launch(void* const* d_in, const int* in_sizes, int n_in,
                              void* d_out, int out_size, void* d_ws, size_t ws_size,
                              hipStream_t stream)
{
    const float* x_graph = (const float*)d_in[0];
    const float* x_m     = (const float*)d_in[1];
    const float* x_job   = (const float*)d_in[2];
    const int*   m_ids   = (const int*)d_in[3];
    const int*   job_idx = (const int*)d_in[4];
    const float* W0      = (const float*)d_in[5];
    const float* b0      = (const float*)d_in[6];
    const float* W1      = (const float*)d_in[7];
    const float* b1      = (const float*)d_in[8];
    const float* W2      = (const float*)d_in[9];
    const float* b2      = (const float*)d_in[10];
    float* out = (float*)d_out;

    const int N = in_sizes[3];
    const int M = in_sizes[1] / HID;
    const int J = in_sizes[2] / HID;

    const int tiles = (N + TILE_R - 1) / TILE_R;         // 3125
    const int aTiles = (M + TILE_P - 1) / TILE_P;        // 32
    const int bTiles = (J + TILE_P - 1) / TILE_P;        // 157
    const int sblocks = (N + 255) / 256;                 // 782

    // ws layout (segments 16-B aligned):
    float* ws = (float*)d_ws;
    float* g = ws;                                        // 128 f
    float* scores = ws + HID;                             // N f
    float4* partials = (float4*)(scores + N);             // tiles f4
    unsigned* misc = (unsigned*)(partials + tiles);       // [0]=gmax [1]=cnt [2:3]=key
    unsigned short* W1T = (unsigned short*)(misc + 4);    // HID*HID shorts
    unsigned short* Pbf = W1T + HID * HID;                // (M+J)*HID shorts

    precompute_kernel<<<1 + aTiles + bTiles + 1, 256, 0, stream>>>(
        x_graph, x_m, x_job, W0, b0, W1, g, Pbf, W1T, misc, M, J, aTiles, bTiles);
    main_kernel<<<MAIN_GRID, 256, 0, stream>>>(
        m_ids, job_idx, b1, W2, b2, g, Pbf, W1T, scores, partials, misc,
        N, M, tiles);
    scan_kernel<<<sblocks, 256, 0, stream>>>(
        partials, tiles, scores, m_ids, job_idx, x_m, x_job, W0, W1, b1, W2, b2,
        g, misc, out, N);
}

// Round 12
// 147.189 us; speedup vs baseline: 1.1086x; 1.1086x over previous
//
#include <hip/hip_runtime.h>
#include <math.h>

#define HID 128
#define TILE_R 64
#define TILE_P 32          // precompute row tile
#define XS_STRIDE 132      // fp32 staging stride (K1)
#define H0S_STRIDE 136     // bf16 LDS stride in shorts: 136*2B row = 68 dwords == 4 mod 32 banks
#define DELTA 0.05f        // per-score qualify margin (R3/R6-validated)

typedef short bf16x8 __attribute__((ext_vector_type(8)));
typedef float f32x4 __attribute__((ext_vector_type(4)));

static __device__ __forceinline__ unsigned short f2bf(float f) {
    union { float f; unsigned u; } v; v.f = f;
    unsigned r = v.u + 0x7FFFu + ((v.u >> 16) & 1u);   // RNE
    return (unsigned short)(r >> 16);
}
static __device__ __forceinline__ float bflo(unsigned u) {
    union { unsigned u; float f; } v; v.u = u << 16; return v.f;
}
static __device__ __forceinline__ float bfhi(unsigned u) {
    union { unsigned u; float f; } v; v.u = u & 0xFFFF0000u; return v.f;
}

#define FMA4(avc, wv)                         \
    acc[r][0] = fmaf(avc, wv.x, acc[r][0]);   \
    acc[r][1] = fmaf(avc, wv.y, acc[r][1]);   \
    acc[r][2] = fmaf(avc, wv.z, acc[r][2]);   \
    acc[r][3] = fmaf(avc, wv.w, acc[r][3]);

// ---------------------------------------------------------------------------
// K1: g = x_graph @ W0[0:256] + b0 (fp32); Pbf = bf16 node partials;
//     W1T[n*128+k] = bf16(W1[k][n]).   (R10-validated)
// ---------------------------------------------------------------------------
__global__ __launch_bounds__(256, 4) void precompute_kernel(
    const float* __restrict__ x_graph,
    const float* __restrict__ x_m,
    const float* __restrict__ x_job,
    const float* __restrict__ W0,
    const float* __restrict__ b0,
    const float* __restrict__ W1,
    float* __restrict__ g,
    unsigned short* __restrict__ Pbf,
    unsigned short* __restrict__ W1T,
    int M, int J, int aTiles, int bTiles)
{
    const int t = threadIdx.x;
    const int bid = blockIdx.x;

    if (bid == 0) {
        __shared__ float xg[2 * HID];
        if (t < HID) { xg[t] = x_graph[t]; xg[t + HID] = x_graph[t + HID]; }
        __syncthreads();
        if (t < HID) {
            float acc = b0[t];
            #pragma unroll 8
            for (int k = 0; k < 2 * HID; ++k)
                acc = fmaf(xg[k], W0[k * HID + t], acc);
            g[t] = acc;
        }
        return;
    }
    if (bid == 1 + aTiles + bTiles) {
        for (int e = t; e < HID * HID; e += 256) {
            int n = e >> 7, k = e & 127;
            W1T[e] = f2bf(W1[k * HID + n]);
        }
        return;
    }

    const int tb = bid - 1;
    const float* X;
    const float* W;
    int r0, nr, dstBase;
    if (tb < aTiles) {
        r0 = tb * TILE_P;
        nr = min(TILE_P, M - r0);
        X = x_m + (size_t)r0 * HID;
        W = W0 + 2 * HID * HID;
        dstBase = r0;
    } else {
        int jb = tb - aTiles;
        r0 = jb * TILE_P;
        nr = min(TILE_P, J - r0);
        X = x_job + (size_t)r0 * HID;
        W = W0 + 3 * HID * HID;
        dstBase = M + r0;
    }

    __shared__ float xs[TILE_P * XS_STRIDE];
    {
        int row = t >> 3;
        int e = t & 7;
        #pragma unroll
        for (int u = 0; u < 4; ++u) {
            int c = e * 16 + u * 4;
            float4 v = (row < nr) ? *(const float4*)(X + row * HID + c)
                                  : make_float4(0.f, 0.f, 0.f, 0.f);
            *(float4*)&xs[row * XS_STRIDE + c] = v;
        }
    }
    __syncthreads();

    const int w = t >> 6;
    const int l = t & 63;
    const int tc = l & 7;
    const int tr = l >> 3;
    const int c0 = w * 32 + tc * 4;

    float acc[4][4];
    #pragma unroll
    for (int r = 0; r < 4; ++r)
        #pragma unroll
        for (int c = 0; c < 4; ++c) acc[r][c] = 0.0f;

    #pragma unroll 2
    for (int k0 = 0; k0 < HID; k0 += 4) {
        float4 w0v = *(const float4*)(W + (k0 + 0) * HID + c0);
        float4 w1v = *(const float4*)(W + (k0 + 1) * HID + c0);
        float4 w2m = *(const float4*)(W + (k0 + 2) * HID + c0);
        float4 w3v = *(const float4*)(W + (k0 + 3) * HID + c0);
        #pragma unroll
        for (int r = 0; r < 4; ++r) {
            float4 a = *(const float4*)&xs[(r * 8 + tr) * XS_STRIDE + k0];
            FMA4(a.x, w0v)
            FMA4(a.y, w1v)
            FMA4(a.z, w2m)
            FMA4(a.w, w3v)
        }
    }

    #pragma unroll
    for (int r = 0; r < 4; ++r) {
        int row = r * 8 + tr;
        if (row < nr) {
            unsigned lo0 = (unsigned)f2bf(acc[r][0]) | ((unsigned)f2bf(acc[r][1]) << 16);
            unsigned lo1 = (unsigned)f2bf(acc[r][2]) | ((unsigned)f2bf(acc[r][3]) << 16);
            uint2 pk = make_uint2(lo0, lo1);
            *(uint2*)(Pbf + (size_t)(dstBase + row) * HID + c0) = pk;
        }
    }
}

// ---------------------------------------------------------------------------
// K2 (R12 rewrite): one 64-row tile per block, W1 IN REGISTERS.
//   Wave w owns cols [w*32, w*32+32) for ALL 64 rows: B = 8 bf16x8 frags
//   (32 VGPRs) loaded from global once at block start (overlaps gather).
//   LDS = h0s only (18.4 KB) -> 4 blocks/CU (vs 2 with w1s = the R11 48us
//   occupancy cap). Per tile: 16 ds_read_b128 A-reads + 32 MFMA / wave.
//   Epilogue: per-quad col-reduction + cross-wave sred sum (R1-validated).
// ---------------------------------------------------------------------------
__global__ __launch_bounds__(256, 4) void main_kernel(
    const int* __restrict__ m_ids,
    const int* __restrict__ job_idx,
    const float* __restrict__ b1,
    const float* __restrict__ W2,
    const float* __restrict__ b2,
    const float* __restrict__ g,
    const unsigned short* __restrict__ Pbf,
    const unsigned short* __restrict__ W1T,
    float* __restrict__ scores,
    float4* __restrict__ partials,
    float* __restrict__ tmax,
    int N, int M)
{
    __shared__ __align__(16) short h0s[TILE_R * H0S_STRIDE];
    __shared__ float sred[4 * TILE_R];

    const int t = threadIdx.x;
    const int l = t & 63;
    const int w = t >> 6;
    const int quad = l >> 4;
    const int mrow = l & 15;
    const int row0 = blockIdx.x * TILE_R;

    // ---- B fragments + epilogue constants (issue first: independent) ----
    bf16x8 bfr[2][4];
    {
        const unsigned short* wb = W1T + (size_t)(w * 32 + mrow) * HID + quad * 8;
        #pragma unroll
        for (int nt = 0; nt < 2; ++nt)
            #pragma unroll
            for (int kc = 0; kc < 4; ++kc)
                bfr[nt][kc] = *(const bf16x8*)(wb + nt * 16 * HID + kc * 32);
    }
    const float b1v0 = b1[w * 32 + mrow];
    const float b1v1 = b1[w * 32 + 16 + mrow];
    const float w2v0 = W2[w * 32 + mrow];
    const float w2v1 = W2[w * 32 + 16 + mrow];

    // ---- stage h0 (bf16): thread t -> row t/4, 32-col quarter t%4 ----
    {
        int row = t >> 2;
        int q = t & 3;
        int grow = row0 + row;
        int gr = (grow < N) ? grow : (N - 1);
        int m = m_ids[gr];
        int j = job_idx[gr];
        const unsigned short* pm = Pbf + (size_t)m * HID + q * 32;
        const unsigned short* pj = Pbf + (size_t)(M + j) * HID + q * 32;
        const float* gp = g + q * 32;
        short* dst = &h0s[row * H0S_STRIDE + q * 32];
        #pragma unroll
        for (int u = 0; u < 4; ++u) {
            uint4 mv = *(const uint4*)(pm + u * 8);
            uint4 jv = *(const uint4*)(pj + u * 8);
            float4 g0 = *(const float4*)(gp + u * 8);
            float4 g1 = *(const float4*)(gp + u * 8 + 4);
            float h0v = fmaxf(bflo(mv.x) + bflo(jv.x) + g0.x, 0.f);
            float h1v = fmaxf(bfhi(mv.x) + bfhi(jv.x) + g0.y, 0.f);
            float h2v = fmaxf(bflo(mv.y) + bflo(jv.y) + g0.z, 0.f);
            float h3v = fmaxf(bfhi(mv.y) + bfhi(jv.y) + g0.w, 0.f);
            float h4v = fmaxf(bflo(mv.z) + bflo(jv.z) + g1.x, 0.f);
            float h5v = fmaxf(bfhi(mv.z) + bfhi(jv.z) + g1.y, 0.f);
            float h6v = fmaxf(bflo(mv.w) + bflo(jv.w) + g1.z, 0.f);
            float h7v = fmaxf(bfhi(mv.w) + bfhi(jv.w) + g1.w, 0.f);
            uint4 pk;
            pk.x = (unsigned)f2bf(h0v) | ((unsigned)f2bf(h1v) << 16);
            pk.y = (unsigned)f2bf(h2v) | ((unsigned)f2bf(h3v) << 16);
            pk.z = (unsigned)f2bf(h4v) | ((unsigned)f2bf(h5v) << 16);
            pk.w = (unsigned)f2bf(h6v) | ((unsigned)f2bf(h7v) << 16);
            *(uint4*)(dst + u * 8) = pk;
        }
    }
    __syncthreads();

    // ---- MFMA: 4 m-tiles x 2 n-tiles; A from LDS, B from registers ----
    f32x4 acc[4][2];
    #pragma unroll
    for (int mt = 0; mt < 4; ++mt) {
        f32x4 z = {0.f, 0.f, 0.f, 0.f};
        acc[mt][0] = z;
        acc[mt][1] = z;
    }
    #pragma unroll
    for (int mt = 0; mt < 4; ++mt) {
        const short* ab = &h0s[(mt * 16 + mrow) * H0S_STRIDE + quad * 8];
        #pragma unroll
        for (int kc = 0; kc < 4; ++kc) {
            bf16x8 af = *(const bf16x8*)(ab + kc * 32);
            acc[mt][0] = __builtin_amdgcn_mfma_f32_16x16x32_bf16(af, bfr[0][kc], acc[mt][0], 0, 0, 0);
            acc[mt][1] = __builtin_amdgcn_mfma_f32_16x16x32_bf16(af, bfr[1][kc], acc[mt][1], 0, 0, 0);
        }
    }

    // ---- epilogue: relu+b1, dot W2; reduce over the 16 cols (mrow lanes) ----
    #pragma unroll
    for (int mt = 0; mt < 4; ++mt) {
        float p[4];
        #pragma unroll
        for (int i = 0; i < 4; ++i) {
            p[i] = fmaxf(acc[mt][0][i] + b1v0, 0.f) * w2v0
                 + fmaxf(acc[mt][1][i] + b1v1, 0.f) * w2v1;
        }
        #pragma unroll
        for (int off = 1; off < 16; off <<= 1) {
            #pragma unroll
            for (int i = 0; i < 4; ++i)
                p[i] += __shfl_xor(p[i], off);
        }
        if (mrow == 0) {
            int rb = mt * 16 + quad * 4;      // row within tile
            sred[w * TILE_R + rb + 0] = p[0];
            sred[w * TILE_R + rb + 1] = p[1];
            sred[w * TILE_R + rb + 2] = p[2];
            sred[w * TILE_R + rb + 3] = p[3];
        }
    }
    __syncthreads();

    // ---- wave 0: combine col-groups, scores + per-block softmax partial ----
    if (t < 64) {
        int grow = row0 + t;
        float s = sred[t] + sred[64 + t] + sred[128 + t] + sred[192 + t] + b2[0];
        if (grow < N) scores[grow] = s;
        else s = -1e30f;

        float mmax = s;
        int midx = grow;
        #pragma unroll
        for (int off = 1; off < 64; off <<= 1) {
            float om = __shfl_xor(mmax, off);
            int oi = __shfl_xor(midx, off);
            if (om > mmax || (om == mmax && oi < midx)) { mmax = om; midx = oi; }
        }
        float d = s - mmax;
        float e = expf(d);
        float z = e;
        float ss = d * e;
        #pragma unroll
        for (int off = 1; off < 64; off <<= 1) {
            z += __shfl_xor(z, off);
            ss += __shfl_xor(ss, off);
        }
        if (t == 0) {
            partials[blockIdx.x] = make_float4(mmax, z, ss, (float)midx);
            tmax[blockIdx.x] = mmax;
        }
    }
}

// ---------------------------------------------------------------------------
__device__ inline void sm_merge(float& am, float& az, float& ass, int& ai,
                                float bm, float bz, float bss, int bi)
{
    if (bm > am || (bm == am && bi < ai)) {
        float tm = am, tz = az, ts = ass; int ti = ai;
        am = bm; az = bz; ass = bss; ai = bi;
        bm = tm; bz = tz; bss = ts; bi = ti;
    }
    float f = expf(bm - am);
    az += bz * f;
    ass += (bss + (bm - am) * bz) * f;
}

// ---------------------------------------------------------------------------
// K3 (R10-validated): fused merge+scan. Each block derives the global cut
//   locally from tmax[] (pure max). Per-block candidates (<=256), exact fp32
//   rescore (register+shfl), best -> bests[b]. No global atomics.
// ---------------------------------------------------------------------------
__global__ __launch_bounds__(256) void scan_kernel(
    const float* __restrict__ tmax, int nparts,
    const float* __restrict__ scores,
    const int* __restrict__ m_ids,
    const int* __restrict__ job_idx,
    const float* __restrict__ x_m,
    const float* __restrict__ x_job,
    const float* __restrict__ W0,
    const float* __restrict__ W1,
    const float* __restrict__ b1,
    const float* __restrict__ W2,
    const float* __restrict__ b2,
    const float* __restrict__ g,
    float2* __restrict__ bests,
    int N)
{
    __shared__ int cand[256];
    __shared__ int ccount;
    __shared__ float rs[4];
    __shared__ int ri[4];
    __shared__ float mmx[4];

    const int t = threadIdx.x;
    const int w = t >> 6;
    const int l = t & 63;
    const int base = blockIdx.x * 256;

    float m0 = -1e30f, m1 = -1e30f, m2 = -1e30f, m3 = -1e30f;
    int i = t;
    for (; i + 768 < nparts; i += 1024) {
        m0 = fmaxf(m0, tmax[i]);
        m1 = fmaxf(m1, tmax[i + 256]);
        m2 = fmaxf(m2, tmax[i + 512]);
        m3 = fmaxf(m3, tmax[i + 768]);
    }
    for (; i < nparts; i += 256) m0 = fmaxf(m0, tmax[i]);
    float mhat = fmaxf(fmaxf(m0, m1), fmaxf(m2, m3));
    #pragma unroll
    for (int off = 1; off < 64; off <<= 1)
        mhat = fmaxf(mhat, __shfl_xor(mhat, off));
    if (l == 0) mmx[w] = mhat;
    if (t == 0) ccount = 0;
    __syncthreads();
    mhat = fmaxf(fmaxf(mmx[0], mmx[1]), fmaxf(mmx[2], mmx[3]));
    const float cut = mhat - DELTA;

    int idx = base + t;
    if (idx < N && scores[idx] >= cut) {
        int p = atomicAdd(&ccount, 1);  // LDS atomic; p < 256 guaranteed
        cand[p] = idx;
    }
    __syncthreads();
    const int nc = ccount;
    if (nc == 0) {
        if (t == 0) bests[blockIdx.x] = make_float2(-1e30f, __int_as_float(0x7fffffff));
        return;
    }

    float bs = -1e30f;
    int bi = 0x7fffffff;
    for (int c = w; c < nc; c += 4) {
        int gr = cand[c];
        int mm = m_ids[gr];
        int jj = job_idx[gr];
        const float* xm = x_m + (size_t)mm * HID;
        const float* xj = x_job + (size_t)jj * HID;
        const float* wm = W0 + 2 * HID * HID;
        const float* wj = W0 + 3 * HID * HID;
        float a0 = g[l], a1 = g[l + 64];
        for (int k = 0; k < HID; ++k) {
            float xmk = xm[k];
            float xjk = xj[k];
            a0 = fmaf(xmk, wm[k * HID + l], a0);
            a1 = fmaf(xmk, wm[k * HID + l + 64], a1);
            a0 = fmaf(xjk, wj[k * HID + l], a0);
            a1 = fmaf(xjk, wj[k * HID + l + 64], a1);
        }
        a0 = fmaxf(a0, 0.f);
        a1 = fmaxf(a1, 0.f);
        float acc0 = 0.f, acc1 = 0.f;
        for (int k = 0; k < 64; ++k) {
            float h = __shfl(a0, k);
            acc0 = fmaf(h, W1[k * HID + l], acc0);
            acc1 = fmaf(h, W1[k * HID + l + 64], acc1);
        }
        for (int k = 0; k < 64; ++k) {
            float h = __shfl(a1, k);
            acc0 = fmaf(h, W1[(k + 64) * HID + l], acc0);
            acc1 = fmaf(h, W1[(k + 64) * HID + l + 64], acc1);
        }
        float p = fmaxf(acc0 + b1[l], 0.f) * W2[l]
                + fmaxf(acc1 + b1[l + 64], 0.f) * W2[l + 64];
        #pragma unroll
        for (int off = 1; off < 64; off <<= 1)
            p += __shfl_xor(p, off);
        float s = p + b2[0];
        if (s > bs || (s == bs && gr < bi)) { bs = s; bi = gr; }
    }
    if (l == 0) { rs[w] = bs; ri[w] = bi; }
    __syncthreads();
    if (t == 0) {
        float best = rs[0];
        int bwin = ri[0];
        for (int i2 = 1; i2 < 4; ++i2)
            if (rs[i2] > best || (rs[i2] == best && ri[i2] < bwin)) {
                best = rs[i2]; bwin = ri[i2];
            }
        bests[blockIdx.x] = make_float2(best, __int_as_float(bwin));
    }
}

// ---------------------------------------------------------------------------
// K4 (1 block, R10-validated): softmax merge of partials + winner -> out.
// ---------------------------------------------------------------------------
__global__ __launch_bounds__(256) void finalize_kernel(
    const float4* __restrict__ partials, int nparts,
    const float2* __restrict__ bests, int nblocks,
    float* __restrict__ out)
{
    __shared__ float4 wred[4];
    __shared__ int widx[4];
    __shared__ float rs[4];
    __shared__ int ri[4];
    const int t = threadIdx.x;
    const int w = t >> 6;
    const int l = t & 63;

    float m = -1e30f, z = 0.f, ss = 0.f;
    int idx = 0x7fffffff;
    for (int i = t; i < nparts; i += 256) {
        float4 p = partials[i];
        sm_merge(m, z, ss, idx, p.x, p.y, p.z, (int)p.w);
    }
    #pragma unroll
    for (int off = 1; off < 64; off <<= 1) {
        float om = __shfl_xor(m, off);
        float oz = __shfl_xor(z, off);
        float os = __shfl_xor(ss, off);
        int oi = __shfl_xor(idx, off);
        sm_merge(m, z, ss, idx, om, oz, os, oi);
    }
    if (l == 0) { wred[w] = make_float4(m, z, ss, 0.f); widx[w] = idx; }

    float bs = -1e30f;
    int bi = 0x7fffffff;
    for (int i = t; i < nblocks; i += 256) {
        float2 b = bests[i];
        int gi = __float_as_int(b.y);
        if (b.x > bs || (b.x == bs && gi < bi)) { bs = b.x; bi = gi; }
    }
    #pragma unroll
    for (int off = 1; off < 64; off <<= 1) {
        float os = __shfl_xor(bs, off);
        int oi = __shfl_xor(bi, off);
        if (os > bs || (os == bs && oi < bi)) { bs = os; bi = oi; }
    }
    if (l == 0) { rs[w] = bs; ri[w] = bi; }
    __syncthreads();

    if (t == 0) {
        for (int i = 1; i < 4; ++i) {
            sm_merge(m, z, ss, idx, wred[i].x, wred[i].y, wred[i].z, widx[i]);
            if (rs[i] > bs || (rs[i] == bs && ri[i] < bi)) { bs = rs[i]; bi = ri[i]; }
        }
        float logZ = logf(z);
        out[0] = (float)bi;             // exact argmax
        out[1] = expf(bs - m) / z;      // probs[idx]
        out[2] = (bs - m) - logZ;       // logp[idx]
        out[3] = logZ - ss / z;         // entropy
    }
}

// ---------------------------------------------------------------------------
extern "C" void kernel_launch(void* const* d_in, const int* in_sizes, int n_in,
                              void* d_out, int out_size, void* d_ws, size_t ws_size,
                              hipStream_t stream)
{
    const float* x_graph = (const float*)d_in[0];
    const float* x_m     = (const float*)d_in[1];
    const float* x_job   = (const float*)d_in[2];
    const int*   m_ids   = (const int*)d_in[3];
    const int*   job_idx = (const int*)d_in[4];
    const float* W0      = (const float*)d_in[5];
    const float* b0      = (const float*)d_in[6];
    const float* W1      = (const float*)d_in[7];
    const float* b1      = (const float*)d_in[8];
    const float* W2      = (const float*)d_in[9];
    const float* b2      = (const float*)d_in[10];
    float* out = (float*)d_out;

    const int N = in_sizes[3];
    const int M = in_sizes[1] / HID;
    const int J = in_sizes[2] / HID;

    const int tiles = (N + TILE_R - 1) / TILE_R;         // 3125
    const int aTiles = (M + TILE_P - 1) / TILE_P;        // 32
    const int bTiles = (J + TILE_P - 1) / TILE_P;        // 157
    const int sblocks = (N + 255) / 256;                 // 782

    // ws layout (segments 16-B aligned):
    float* ws = (float*)d_ws;
    float* g = ws;                                        // 128 f
    float* scores = ws + HID;                             // N f
    float4* partials = (float4*)(scores + N);             // tiles f4
    float* tmax = (float*)(partials + tiles);             // tiles f
    const int tmaxPad = (tiles + 3) & ~3;
    float2* bests = (float2*)(tmax + tmaxPad);            // sblocks f2
    unsigned short* W1T = (unsigned short*)(bests + sblocks + (sblocks & 1)); // HID*HID shorts
    unsigned short* Pbf = W1T + HID * HID;                // (M+J)*HID shorts

    precompute_kernel<<<1 + aTiles + bTiles + 1, 256, 0, stream>>>(
        x_graph, x_m, x_job, W0, b0, W1, g, Pbf, W1T, M, J, aTiles, bTiles);
    main_kernel<<<tiles, 256, 0, stream>>>(
        m_ids, job_idx, b1, W2, b2, g, Pbf, W1T, scores, partials, tmax, N, M);
    scan_kernel<<<sblocks, 256, 0, stream>>>(
        tmax, tiles, scores, m_ids, job_idx, x_m, x_job, W0, W1, b1, W2, b2,
        g, bests, N);
    finalize_kernel<<<1, 256, 0, stream>>>(partials, tiles, bests, sblocks, out);
}

// Round 13
// 139.744 us; speedup vs baseline: 1.1677x; 1.0533x over previous
//
#include <hip/hip_runtime.h>
#include <math.h>

#define HID 128
#define TILE_R 64
#define TILE_P 32          // precompute row tile
#define XS_STRIDE 132      // fp32 staging stride (K1)
#define H0S_STRIDE 136     // bf16 LDS stride in shorts: 136*2B row = 68 dwords == 4 mod 32 banks
#define DELTA 0.05f        // per-score qualify margin (R3/R6-validated)
#define MAIN_GRID 1024     // 4 blocks/CU co-resident persistent main (R12 occupancy + R10 persistence)

typedef short bf16x8 __attribute__((ext_vector_type(8)));
typedef float f32x4 __attribute__((ext_vector_type(4)));

static __device__ __forceinline__ unsigned short f2bf(float f) {
    union { float f; unsigned u; } v; v.f = f;
    unsigned r = v.u + 0x7FFFu + ((v.u >> 16) & 1u);   // RNE
    return (unsigned short)(r >> 16);
}
static __device__ __forceinline__ float bflo(unsigned u) {
    union { unsigned u; float f; } v; v.u = u << 16; return v.f;
}
static __device__ __forceinline__ float bfhi(unsigned u) {
    union { unsigned u; float f; } v; v.u = u & 0xFFFF0000u; return v.f;
}

#define FMA4(avc, wv)                         \
    acc[r][0] = fmaf(avc, wv.x, acc[r][0]);   \
    acc[r][1] = fmaf(avc, wv.y, acc[r][1]);   \
    acc[r][2] = fmaf(avc, wv.z, acc[r][2]);   \
    acc[r][3] = fmaf(avc, wv.w, acc[r][3]);

// ---------------------------------------------------------------------------
// K1: g = x_graph @ W0[0:256] + b0 (fp32); Pbf = bf16 node partials;
//     W1T[n*128+k] = bf16(W1[k][n]).   (R10/R12-validated)
// ---------------------------------------------------------------------------
__global__ __launch_bounds__(256, 4) void precompute_kernel(
    const float* __restrict__ x_graph,
    const float* __restrict__ x_m,
    const float* __restrict__ x_job,
    const float* __restrict__ W0,
    const float* __restrict__ b0,
    const float* __restrict__ W1,
    float* __restrict__ g,
    unsigned short* __restrict__ Pbf,
    unsigned short* __restrict__ W1T,
    int M, int J, int aTiles, int bTiles)
{
    const int t = threadIdx.x;
    const int bid = blockIdx.x;

    if (bid == 0) {
        __shared__ float xg[2 * HID];
        if (t < HID) { xg[t] = x_graph[t]; xg[t + HID] = x_graph[t + HID]; }
        __syncthreads();
        if (t < HID) {
            float acc = b0[t];
            #pragma unroll 8
            for (int k = 0; k < 2 * HID; ++k)
                acc = fmaf(xg[k], W0[k * HID + t], acc);
            g[t] = acc;
        }
        return;
    }
    if (bid == 1 + aTiles + bTiles) {
        for (int e = t; e < HID * HID; e += 256) {
            int n = e >> 7, k = e & 127;
            W1T[e] = f2bf(W1[k * HID + n]);
        }
        return;
    }

    const int tb = bid - 1;
    const float* X;
    const float* W;
    int r0, nr, dstBase;
    if (tb < aTiles) {
        r0 = tb * TILE_P;
        nr = min(TILE_P, M - r0);
        X = x_m + (size_t)r0 * HID;
        W = W0 + 2 * HID * HID;
        dstBase = r0;
    } else {
        int jb = tb - aTiles;
        r0 = jb * TILE_P;
        nr = min(TILE_P, J - r0);
        X = x_job + (size_t)r0 * HID;
        W = W0 + 3 * HID * HID;
        dstBase = M + r0;
    }

    __shared__ float xs[TILE_P * XS_STRIDE];
    {
        int row = t >> 3;
        int e = t & 7;
        #pragma unroll
        for (int u = 0; u < 4; ++u) {
            int c = e * 16 + u * 4;
            float4 v = (row < nr) ? *(const float4*)(X + row * HID + c)
                                  : make_float4(0.f, 0.f, 0.f, 0.f);
            *(float4*)&xs[row * XS_STRIDE + c] = v;
        }
    }
    __syncthreads();

    const int w = t >> 6;
    const int l = t & 63;
    const int tc = l & 7;
    const int tr = l >> 3;
    const int c0 = w * 32 + tc * 4;

    float acc[4][4];
    #pragma unroll
    for (int r = 0; r < 4; ++r)
        #pragma unroll
        for (int c = 0; c < 4; ++c) acc[r][c] = 0.0f;

    #pragma unroll 2
    for (int k0 = 0; k0 < HID; k0 += 4) {
        float4 w0v = *(const float4*)(W + (k0 + 0) * HID + c0);
        float4 w1v = *(const float4*)(W + (k0 + 1) * HID + c0);
        float4 w2m = *(const float4*)(W + (k0 + 2) * HID + c0);
        float4 w3v = *(const float4*)(W + (k0 + 3) * HID + c0);
        #pragma unroll
        for (int r = 0; r < 4; ++r) {
            float4 a = *(const float4*)&xs[(r * 8 + tr) * XS_STRIDE + k0];
            FMA4(a.x, w0v)
            FMA4(a.y, w1v)
            FMA4(a.z, w2m)
            FMA4(a.w, w3v)
        }
    }

    #pragma unroll
    for (int r = 0; r < 4; ++r) {
        int row = r * 8 + tr;
        if (row < nr) {
            unsigned lo0 = (unsigned)f2bf(acc[r][0]) | ((unsigned)f2bf(acc[r][1]) << 16);
            unsigned lo1 = (unsigned)f2bf(acc[r][2]) | ((unsigned)f2bf(acc[r][3]) << 16);
            uint2 pk = make_uint2(lo0, lo1);
            *(uint2*)(Pbf + (size_t)(dstBase + row) * HID + c0) = pk;
        }
    }
}

// ---------------------------------------------------------------------------
// K2 (R13): persistent reg-B main. Wave w owns cols [w*32,w*32+32) for all
//   64 rows; B = 8 bf16x8 frags (32 VGPRs) loaded ONCE per block from W1T,
//   then grid-stride over ~3 tiles (amortizes B-load + setup; R10-validated
//   loop barrier structure). LDS = h0s only (18.4 KB) -> 4 blocks/CU.
// ---------------------------------------------------------------------------
__global__ __launch_bounds__(256, 4) void main_kernel(
    const int* __restrict__ m_ids,
    const int* __restrict__ job_idx,
    const float* __restrict__ b1,
    const float* __restrict__ W2,
    const float* __restrict__ b2,
    const float* __restrict__ g,
    const unsigned short* __restrict__ Pbf,
    const unsigned short* __restrict__ W1T,
    float* __restrict__ scores,
    float4* __restrict__ partials,
    float* __restrict__ tmax,
    int N, int M, int tiles)
{
    __shared__ __align__(16) short h0s[TILE_R * H0S_STRIDE];
    __shared__ float sred[4 * TILE_R];

    const int t = threadIdx.x;
    const int l = t & 63;
    const int w = t >> 6;
    const int quad = l >> 4;
    const int mrow = l & 15;

    // ---- B fragments + epilogue constants: once per block ----
    bf16x8 bfr[2][4];
    {
        const unsigned short* wb = W1T + (size_t)(w * 32 + mrow) * HID + quad * 8;
        #pragma unroll
        for (int nt = 0; nt < 2; ++nt)
            #pragma unroll
            for (int kc = 0; kc < 4; ++kc)
                bfr[nt][kc] = *(const bf16x8*)(wb + nt * 16 * HID + kc * 32);
    }
    const float b1v0 = b1[w * 32 + mrow];
    const float b1v1 = b1[w * 32 + 16 + mrow];
    const float w2v0 = W2[w * 32 + mrow];
    const float w2v1 = W2[w * 32 + 16 + mrow];
    const float b2v = b2[0];

    for (int tile = blockIdx.x; tile < tiles; tile += MAIN_GRID) {
        const int row0 = tile * TILE_R;

        // ---- stage h0 (bf16): thread t -> row t/4, 32-col quarter t%4 ----
        {
            int row = t >> 2;
            int q = t & 3;
            int grow = row0 + row;
            int gr = (grow < N) ? grow : (N - 1);
            int m = m_ids[gr];
            int j = job_idx[gr];
            const unsigned short* pm = Pbf + (size_t)m * HID + q * 32;
            const unsigned short* pj = Pbf + (size_t)(M + j) * HID + q * 32;
            const float* gp = g + q * 32;
            short* dst = &h0s[row * H0S_STRIDE + q * 32];
            #pragma unroll
            for (int u = 0; u < 4; ++u) {
                uint4 mv = *(const uint4*)(pm + u * 8);
                uint4 jv = *(const uint4*)(pj + u * 8);
                float4 g0 = *(const float4*)(gp + u * 8);
                float4 g1 = *(const float4*)(gp + u * 8 + 4);
                float h0v = fmaxf(bflo(mv.x) + bflo(jv.x) + g0.x, 0.f);
                float h1v = fmaxf(bfhi(mv.x) + bfhi(jv.x) + g0.y, 0.f);
                float h2v = fmaxf(bflo(mv.y) + bflo(jv.y) + g0.z, 0.f);
                float h3v = fmaxf(bfhi(mv.y) + bfhi(jv.y) + g0.w, 0.f);
                float h4v = fmaxf(bflo(mv.z) + bflo(jv.z) + g1.x, 0.f);
                float h5v = fmaxf(bfhi(mv.z) + bfhi(jv.z) + g1.y, 0.f);
                float h6v = fmaxf(bflo(mv.w) + bflo(jv.w) + g1.z, 0.f);
                float h7v = fmaxf(bfhi(mv.w) + bfhi(jv.w) + g1.w, 0.f);
                uint4 pk;
                pk.x = (unsigned)f2bf(h0v) | ((unsigned)f2bf(h1v) << 16);
                pk.y = (unsigned)f2bf(h2v) | ((unsigned)f2bf(h3v) << 16);
                pk.z = (unsigned)f2bf(h4v) | ((unsigned)f2bf(h5v) << 16);
                pk.w = (unsigned)f2bf(h6v) | ((unsigned)f2bf(h7v) << 16);
                *(uint4*)(dst + u * 8) = pk;
            }
        }
        __syncthreads();                       // barrier 1: h0s ready

        // ---- MFMA: 4 m-tiles x 2 n-tiles; A from LDS, B from registers ----
        f32x4 acc[4][2];
        #pragma unroll
        for (int mt = 0; mt < 4; ++mt) {
            f32x4 z = {0.f, 0.f, 0.f, 0.f};
            acc[mt][0] = z;
            acc[mt][1] = z;
        }
        #pragma unroll
        for (int mt = 0; mt < 4; ++mt) {
            const short* ab = &h0s[(mt * 16 + mrow) * H0S_STRIDE + quad * 8];
            #pragma unroll
            for (int kc = 0; kc < 4; ++kc) {
                bf16x8 af = *(const bf16x8*)(ab + kc * 32);
                acc[mt][0] = __builtin_amdgcn_mfma_f32_16x16x32_bf16(af, bfr[0][kc], acc[mt][0], 0, 0, 0);
                acc[mt][1] = __builtin_amdgcn_mfma_f32_16x16x32_bf16(af, bfr[1][kc], acc[mt][1], 0, 0, 0);
            }
        }

        // ---- epilogue: relu+b1, dot W2; reduce over 16 cols (mrow lanes) ----
        #pragma unroll
        for (int mt = 0; mt < 4; ++mt) {
            float p[4];
            #pragma unroll
            for (int i = 0; i < 4; ++i) {
                p[i] = fmaxf(acc[mt][0][i] + b1v0, 0.f) * w2v0
                     + fmaxf(acc[mt][1][i] + b1v1, 0.f) * w2v1;
            }
            #pragma unroll
            for (int off = 1; off < 16; off <<= 1) {
                #pragma unroll
                for (int i = 0; i < 4; ++i)
                    p[i] += __shfl_xor(p[i], off);
            }
            if (mrow == 0) {
                int rb = mt * 16 + quad * 4;
                sred[w * TILE_R + rb + 0] = p[0];
                sred[w * TILE_R + rb + 1] = p[1];
                sred[w * TILE_R + rb + 2] = p[2];
                sred[w * TILE_R + rb + 3] = p[3];
            }
        }
        __syncthreads();                       // barrier 2: sred ready; h0s free

        // ---- wave 0: combine col-groups, scores + softmax partial ----
        if (t < 64) {
            int grow = row0 + t;
            float s = sred[t] + sred[64 + t] + sred[128 + t] + sred[192 + t] + b2v;
            if (grow < N) scores[grow] = s;
            else s = -1e30f;

            float mmax = s;
            int midx = grow;
            #pragma unroll
            for (int off = 1; off < 64; off <<= 1) {
                float om = __shfl_xor(mmax, off);
                int oi = __shfl_xor(midx, off);
                if (om > mmax || (om == mmax && oi < midx)) { mmax = om; midx = oi; }
            }
            float d = s - mmax;
            float e = expf(d);
            float z = e;
            float ss = d * e;
            #pragma unroll
            for (int off = 1; off < 64; off <<= 1) {
                z += __shfl_xor(z, off);
                ss += __shfl_xor(ss, off);
            }
            if (t == 0) {
                partials[tile] = make_float4(mmax, z, ss, (float)midx);
                tmax[tile] = mmax;
            }
        }
        // sred reads above happen before next iteration's barrier 1, and the
        // next sred writes happen after it -> no WAR hazard (R10-validated).
    }
}

// ---------------------------------------------------------------------------
__device__ inline void sm_merge(float& am, float& az, float& ass, int& ai,
                                float bm, float bz, float bss, int bi)
{
    if (bm > am || (bm == am && bi < ai)) {
        float tm = am, tz = az, ts = ass; int ti = ai;
        am = bm; az = bz; ass = bss; ai = bi;
        bm = tm; bz = tz; bss = ts; bi = ti;
    }
    float f = expf(bm - am);
    az += bz * f;
    ass += (bss + (bm - am) * bz) * f;
}

// ---------------------------------------------------------------------------
// K3 (R10-validated): fused merge+scan. Cut derived locally from tmax[]
//   (pure max). Per-block candidates (<=256), exact fp32 rescore
//   (register+shfl), best -> bests[b]. No global atomics.
// ---------------------------------------------------------------------------
__global__ __launch_bounds__(256) void scan_kernel(
    const float* __restrict__ tmax, int nparts,
    const float* __restrict__ scores,
    const int* __restrict__ m_ids,
    const int* __restrict__ job_idx,
    const float* __restrict__ x_m,
    const float* __restrict__ x_job,
    const float* __restrict__ W0,
    const float* __restrict__ W1,
    const float* __restrict__ b1,
    const float* __restrict__ W2,
    const float* __restrict__ b2,
    const float* __restrict__ g,
    float2* __restrict__ bests,
    int N)
{
    __shared__ int cand[256];
    __shared__ int ccount;
    __shared__ float rs[4];
    __shared__ int ri[4];
    __shared__ float mmx[4];

    const int t = threadIdx.x;
    const int w = t >> 6;
    const int l = t & 63;
    const int base = blockIdx.x * 256;

    float m0 = -1e30f, m1 = -1e30f, m2 = -1e30f, m3 = -1e30f;
    int i = t;
    for (; i + 768 < nparts; i += 1024) {
        m0 = fmaxf(m0, tmax[i]);
        m1 = fmaxf(m1, tmax[i + 256]);
        m2 = fmaxf(m2, tmax[i + 512]);
        m3 = fmaxf(m3, tmax[i + 768]);
    }
    for (; i < nparts; i += 256) m0 = fmaxf(m0, tmax[i]);
    float mhat = fmaxf(fmaxf(m0, m1), fmaxf(m2, m3));
    #pragma unroll
    for (int off = 1; off < 64; off <<= 1)
        mhat = fmaxf(mhat, __shfl_xor(mhat, off));
    if (l == 0) mmx[w] = mhat;
    if (t == 0) ccount = 0;
    __syncthreads();
    mhat = fmaxf(fmaxf(mmx[0], mmx[1]), fmaxf(mmx[2], mmx[3]));
    const float cut = mhat - DELTA;

    int idx = base + t;
    if (idx < N && scores[idx] >= cut) {
        int p = atomicAdd(&ccount, 1);  // LDS atomic; p < 256 guaranteed
        cand[p] = idx;
    }
    __syncthreads();
    const int nc = ccount;
    if (nc == 0) {
        if (t == 0) bests[blockIdx.x] = make_float2(-1e30f, __int_as_float(0x7fffffff));
        return;
    }

    float bs = -1e30f;
    int bi = 0x7fffffff;
    for (int c = w; c < nc; c += 4) {
        int gr = cand[c];
        int mm = m_ids[gr];
        int jj = job_idx[gr];
        const float* xm = x_m + (size_t)mm * HID;
        const float* xj = x_job + (size_t)jj * HID;
        const float* wm = W0 + 2 * HID * HID;
        const float* wj = W0 + 3 * HID * HID;
        float a0 = g[l], a1 = g[l + 64];
        for (int k = 0; k < HID; ++k) {
            float xmk = xm[k];
            float xjk = xj[k];
            a0 = fmaf(xmk, wm[k * HID + l], a0);
            a1 = fmaf(xmk, wm[k * HID + l + 64], a1);
            a0 = fmaf(xjk, wj[k * HID + l], a0);
            a1 = fmaf(xjk, wj[k * HID + l + 64], a1);
        }
        a0 = fmaxf(a0, 0.f);
        a1 = fmaxf(a1, 0.f);
        float acc0 = 0.f, acc1 = 0.f;
        for (int k = 0; k < 64; ++k) {
            float h = __shfl(a0, k);
            acc0 = fmaf(h, W1[k * HID + l], acc0);
            acc1 = fmaf(h, W1[k * HID + l + 64], acc1);
        }
        for (int k = 0; k < 64; ++k) {
            float h = __shfl(a1, k);
            acc0 = fmaf(h, W1[(k + 64) * HID + l], acc0);
            acc1 = fmaf(h, W1[(k + 64) * HID + l + 64], acc1);
        }
        float p = fmaxf(acc0 + b1[l], 0.f) * W2[l]
                + fmaxf(acc1 + b1[l + 64], 0.f) * W2[l + 64];
        #pragma unroll
        for (int off = 1; off < 64; off <<= 1)
            p += __shfl_xor(p, off);
        float s = p + b2[0];
        if (s > bs || (s == bs && gr < bi)) { bs = s; bi = gr; }
    }
    if (l == 0) { rs[w] = bs; ri[w] = bi; }
    __syncthreads();
    if (t == 0) {
        float best = rs[0];
        int bwin = ri[0];
        for (int i2 = 1; i2 < 4; ++i2)
            if (rs[i2] > best || (rs[i2] == best && ri[i2] < bwin)) {
                best = rs[i2]; bwin = ri[i2];
            }
        bests[blockIdx.x] = make_float2(best, __int_as_float(bwin));
    }
}

// ---------------------------------------------------------------------------
// K4 (1 block, R10-validated): softmax merge of partials + winner -> out.
// ---------------------------------------------------------------------------
__global__ __launch_bounds__(256) void finalize_kernel(
    const float4* __restrict__ partials, int nparts,
    const float2* __restrict__ bests, int nblocks,
    float* __restrict__ out)
{
    __shared__ float4 wred[4];
    __shared__ int widx[4];
    __shared__ float rs[4];
    __shared__ int ri[4];
    const int t = threadIdx.x;
    const int w = t >> 6;
    const int l = t & 63;

    float m = -1e30f, z = 0.f, ss = 0.f;
    int idx = 0x7fffffff;
    for (int i = t; i < nparts; i += 256) {
        float4 p = partials[i];
        sm_merge(m, z, ss, idx, p.x, p.y, p.z, (int)p.w);
    }
    #pragma unroll
    for (int off = 1; off < 64; off <<= 1) {
        float om = __shfl_xor(m, off);
        float oz = __shfl_xor(z, off);
        float os = __shfl_xor(ss, off);
        int oi = __shfl_xor(idx, off);
        sm_merge(m, z, ss, idx, om, oz, os, oi);
    }
    if (l == 0) { wred[w] = make_float4(m, z, ss, 0.f); widx[w] = idx; }

    float bs = -1e30f;
    int bi = 0x7fffffff;
    for (int i = t; i < nblocks; i += 256) {
        float2 b = bests[i];
        int gi = __float_as_int(b.y);
        if (b.x > bs || (b.x == bs && gi < bi)) { bs = b.x; bi = gi; }
    }
    #pragma unroll
    for (int off = 1; off < 64; off <<= 1) {
        float os = __shfl_xor(bs, off);
        int oi = __shfl_xor(bi, off);
        if (os > bs || (os == bs && oi < bi)) { bs = os; bi = oi; }
    }
    if (l == 0) { rs[w] = bs; ri[w] = bi; }
    __syncthreads();

    if (t == 0) {
        for (int i = 1; i < 4; ++i) {
            sm_merge(m, z, ss, idx, wred[i].x, wred[i].y, wred[i].z, widx[i]);
            if (rs[i] > bs || (rs[i] == bs && ri[i] < bi)) { bs = rs[i]; bi = ri[i]; }
        }
        float logZ = logf(z);
        out[0] = (float)bi;             // exact argmax
        out[1] = expf(bs - m) / z;      // probs[idx]
        out[2] = (bs - m) - logZ;       // logp[idx]
        out[3] = logZ - ss / z;         // entropy
    }
}

// ---------------------------------------------------------------------------
extern "C" void kernel_launch(void* const* d_in, const int* in_sizes, int n_in,
                              void* d_out, int out_size, void* d_ws, size_t ws_size,
                              hipStream_t stream)
{
    const float* x_graph = (const float*)d_in[0];
    const float* x_m     = (const float*)d_in[1];
    const float* x_job   = (const float*)d_in[2];
    const int*   m_ids   = (const int*)d_in[3];
    const int*   job_idx = (const int*)d_in[4];
    const float* W0      = (const float*)d_in[5];
    const float* b0      = (const float*)d_in[6];
    const float* W1      = (const float*)d_in[7];
    const float* b1      = (const float*)d_in[8];
    const float* W2      = (const float*)d_in[9];
    const float* b2      = (const float*)d_in[10];
    float* out = (float*)d_out;

    const int N = in_sizes[3];
    const int M = in_sizes[1] / HID;
    const int J = in_sizes[2] / HID;

    const int tiles = (N + TILE_R - 1) / TILE_R;         // 3125
    const int aTiles = (M + TILE_P - 1) / TILE_P;        // 32
    const int bTiles = (J + TILE_P - 1) / TILE_P;        // 157
    const int sblocks = (N + 255) / 256;                 // 782

    // ws layout (segments 16-B aligned):
    float* ws = (float*)d_ws;
    float* g = ws;                                        // 128 f
    float* scores = ws + HID;                             // N f
    float4* partials = (float4*)(scores + N);             // tiles f4
    float* tmax = (float*)(partials + tiles);             // tiles f
    const int tmaxPad = (tiles + 3) & ~3;
    float2* bests = (float2*)(tmax + tmaxPad);            // sblocks f2
    unsigned short* W1T = (unsigned short*)(bests + sblocks + (sblocks & 1)); // HID*HID shorts
    unsigned short* Pbf = W1T + HID * HID;                // (M+J)*HID shorts

    precompute_kernel<<<1 + aTiles + bTiles + 1, 256, 0, stream>>>(
        x_graph, x_m, x_job, W0, b0, W1, g, Pbf, W1T, M, J, aTiles, bTiles);
    main_kernel<<<MAIN_GRID, 256, 0, stream>>>(
        m_ids, job_idx, b1, W2, b2, g, Pbf, W1T, scores, partials, tmax,
        N, M, tiles);
    scan_kernel<<<sblocks, 256, 0, stream>>>(
        tmax, tiles, scores, m_ids, job_idx, x_m, x_job, W0, W1, b1, W2, b2,
        g, bests, N);
    finalize_kernel<<<1, 256, 0, stream>>>(partials, tiles, bests, sblocks, out);
}